// Round 3
// baseline (309.666 us; speedup 1.0000x reference)
//
#include <hip/hip_runtime.h>

typedef __bf16 bf16;
typedef __bf16 bf16x8 __attribute__((ext_vector_type(8)));
typedef __bf16 bf16x4 __attribute__((ext_vector_type(4)));
typedef float  f32x4  __attribute__((ext_vector_type(4)));

#define T_TOTAL 9792
#define EMBED   1024
#define NHEAD   16
#define HDIM    64

// Fixed problem geometry (LENGTHS are compile-time constants of this problem).
__constant__ int c_seq_start[12] = {0,1024,1792,2688,3200,4224,4864,5888,6656,7168,8064,9088};
__constant__ int c_tiles_cum[13] = {0,16,28,42,50,66,76,92,104,112,126,142,153};

typedef __attribute__((address_space(1))) unsigned int gu32;
typedef __attribute__((address_space(3))) unsigned int lu32;

__device__ __forceinline__ void load_lds16(const void* g, void* l) {
    __builtin_amdgcn_global_load_lds((gu32*)g, (lu32*)l, 16, 0, 0);
}

__device__ __forceinline__ f32x4 mfma16(bf16x8 a, bf16x8 b, f32x4 c) {
    return __builtin_amdgcn_mfma_f32_16x16x32_bf16(a, b, c, 0, 0, 0);
}

// ---------------------------------------------------------------------------
// Fused dtype canonicalization: all 10 tensors in one dispatch.
// Discriminator: cos[0][0]==1.0 exactly -> fp32 first u16 is 0x0000.
// ---------------------------------------------------------------------------
struct CvtArgs {
    const void* src[10];
    bf16*       dst[10];
    int         n[10];
    int         cum[10];   // block offset of each segment
};

__global__ void to_bf16_fused(CvtArgs a, const unsigned short* __restrict__ disc)
{
    const bool f32 = (disc[0] == 0);
    const int blk = blockIdx.x;
    int seg = 0;
    #pragma unroll
    for (int i = 1; i < 10; ++i) if (blk >= a.cum[i]) seg = i;
    int i0 = (blk - a.cum[seg]) * 2048 + threadIdx.x * 8;
    if (i0 >= a.n[seg]) return;
    bf16x8 o;
    if (f32) {
        const float4* s = (const float4*)((const float*)a.src[seg] + i0);
        float4 x = s[0], y = s[1];
        o[0]=(bf16)x.x; o[1]=(bf16)x.y; o[2]=(bf16)x.z; o[3]=(bf16)x.w;
        o[4]=(bf16)y.x; o[5]=(bf16)y.y; o[6]=(bf16)y.z; o[7]=(bf16)y.w;
    } else {
        o = *(const bf16x8*)((const bf16*)a.src[seg] + i0);
    }
    *(bf16x8*)(a.dst[seg] + i0) = o;
}

// Supertile block map: 8 x-tiles per super-column x all NY, L2/L3 locality.
// 77 x-tiles: 9 full supercols of 8 + tail of 5.
__device__ __forceinline__ void map_block(int L, int NY, int& x, int& y)
{
    const int per = 8 * NY;
    const int full = 9 * per;          // 72 of 77 x-tiles in full supercols
    if (L < full) { int sc = L / per, rem = L % per; x = sc * 8 + (rem & 7); y = rem >> 3; }
    else          { int rem = L - full; x = 72 + rem % 5; y = rem / 5; }
}

// ---------------------------------------------------------------------------
// 128x128 4-wave GEMM core, BK=32, 4-buffer / 3-deep counted-vmcnt pipeline.
//   body(t): vmcnt(8) [own oldest tile's 4 loads landed; 2 tiles stay in
//   flight] -> s_barrier [all waves' tile-t loads landed] -> stage(t+3) into
//   buf (t+3)&3 = (t-1)&3 [WAR-safe: every wave consumed its tile-(t-1)
//   reads before its barrier] -> 8 ds_read_b128 -> 16 MFMA (setprio-wrapped).
//   NEVER drains vmcnt to 0 until the tail. 2 blocks/CU co-resident (64 KiB
//   LDS/block) so the two blocks' phases interleave on MFMA/LDS pipes (m114).
// Bank swizzle (fixes R2's 5.75M conflicts): LDS(row, g) holds global
//   granule g ^ ((row>>1)&3); inverse perm applied on the GLOBAL source
//   (LDS dest stays linear for global_load_lds), reads XOR the same term.
//   Quarter-wave lanes then cover all 8 bank-quads 2-way (free).
// ---------------------------------------------------------------------------
__device__ __forceinline__
void gemm_core128(const bf16* __restrict__ A, const bf16* __restrict__ W,
                  int M, int m0, int n0, f32x4 (&acc)[4][4], bf16* lds)
{
    const int tid  = threadIdx.x;
    const int wave = tid >> 6, lane = tid & 63;
    const int ln   = lane & 15, lq = lane >> 4;
    const int wm   = (wave & 1) * 64, wn = (wave >> 1) * 64;

    // staging map: thread -> (srow = tid>>2 in [0,64), g = tid&3), rows srow
    // and srow+64 of both matrices; 16B per load; LDS dest = tid*8 elems.
    const int sgsw = ((tid & 3) ^ ((tid >> 3) & 3)) * 8;   // swizzled source granule
    int rr0 = m0 + (tid >> 2);       if (rr0 > M - 1) rr0 = M - 1;
    int rr1 = m0 + 64 + (tid >> 2);  if (rr1 > M - 1) rr1 = M - 1;
    const bf16* gA0 = A + (size_t)rr0 * EMBED + sgsw;
    const bf16* gA1 = A + (size_t)rr1 * EMBED + sgsw;
    const bf16* gB0 = W + (size_t)(n0 + (tid >> 2)) * EMBED + sgsw;
    const bf16* gB1 = W + (size_t)(n0 + 64 + (tid >> 2)) * EMBED + sgsw;

    auto stage = [&](int t) {
        const int k0 = t * 32;
        bf16* dA = lds + (t & 3) * 8192;       // per buf: 4096 A + 4096 B elems
        bf16* dB = dA + 4096;
        load_lds16(gA0 + k0, dA + tid * 8);
        load_lds16(gA1 + k0, dA + 2048 + tid * 8);
        load_lds16(gB0 + k0, dB + tid * 8);
        load_lds16(gB1 + k0, dB + 2048 + tid * 8);
    };

    stage(0); stage(1); stage(2);

    const int rsw  = (lq ^ ((ln >> 1) & 3)) * 8;
    const int aoff = (wm + ln) * 32 + rsw;
    const int boff = (wn + ln) * 32 + rsw;

    for (int t = 0; t < 32; ++t) {
        if (t < 30)       asm volatile("s_waitcnt vmcnt(8)" ::: "memory");
        else if (t == 30) asm volatile("s_waitcnt vmcnt(4)" ::: "memory");
        else              asm volatile("s_waitcnt vmcnt(0)" ::: "memory");
        asm volatile("s_barrier" ::: "memory");
        if (t + 3 < 32) stage(t + 3);

        const bf16* sA = lds + (t & 3) * 8192;
        const bf16* sB = sA + 4096;
        bf16x8 af[4], bfr[4];
        #pragma unroll
        for (int mi = 0; mi < 4; ++mi)
            af[mi]  = *(const bf16x8*)&sA[aoff + mi * 512];
        #pragma unroll
        for (int ni = 0; ni < 4; ++ni)
            bfr[ni] = *(const bf16x8*)&sB[boff + ni * 512];

        __builtin_amdgcn_s_setprio(1);
        #pragma unroll
        for (int mi = 0; mi < 4; ++mi)
            #pragma unroll
            for (int ni = 0; ni < 4; ++ni)
                acc[mi][ni] = mfma16(af[mi], bfr[ni], acc[mi][ni]);
        __builtin_amdgcn_s_setprio(0);
    }
}

// ---------------------------------------------------------------------------
// QKV fused GEMM. 1D grid 77*24. which = y>>3 selects {Q,K,V}.
// Epilogue fuses: bias add, RoPE (Q,K; on fp32 acc), V transpose -> Vt.
// ---------------------------------------------------------------------------
__global__ __launch_bounds__(256, 2)
void gemm_qkv(const bf16* __restrict__ A,
              const bf16* __restrict__ Wq, const bf16* __restrict__ Wk,
              const bf16* __restrict__ Wv, const bf16* __restrict__ qb,
              const bf16* __restrict__ vb,
              const bf16* __restrict__ cosb, const bf16* __restrict__ sinb,
              bf16* __restrict__ Cq, bf16* __restrict__ Ck,
              bf16* __restrict__ Vt, int M)
{
    __shared__ __align__(16) bf16 lds[4 * 8192];

    int x, yy;
    map_block(blockIdx.x, 24, x, yy);
    const int which = yy >> 3;
    const int m0 = x * 128, n0 = (yy & 7) * 128;

    const bf16* W = (which == 0) ? Wq : (which == 1) ? Wk : Wv;
    f32x4 acc[4][4] = {};
    gemm_core128(A, W, M, m0, n0, acc, lds);

    const int tid  = threadIdx.x;
    const int wave = tid >> 6, lane = tid & 63;
    const int ln   = lane & 15, lq = lane >> 4;
    const int wm = (wave & 1) * 64,  wn = (wave >> 1) * 64;

    if (which < 2) {
        // Q or K: bias (Q only) + RoPE on fp32 acc. Pair (d, d+32) = (ni, ni+2).
        bf16* C = (which == 0) ? Cq : Ck;
        const bf16* bias = (which == 0) ? qb : nullptr;
        #pragma unroll
        for (int mi = 0; mi < 4; ++mi) {
            int trow = m0 + wm + mi * 16 + lq * 4;
            if (trow >= M) continue;
            #pragma unroll
            for (int ni = 0; ni < 2; ++ni) {
                int d    = ni * 16 + ln;           // in [0,32)
                int col0 = n0 + wn + d;
                int col1 = col0 + 32;
                float b0 = bias ? (float)bias[col0] : 0.0f;
                float b1 = bias ? (float)bias[col1] : 0.0f;
                #pragma unroll
                for (int r = 0; r < 4; ++r) {
                    int t = trow + r;
                    float c = (float)cosb[t * HDIM + d];
                    float s = (float)sinb[t * HDIM + d];
                    float x0 = acc[mi][ni][r] + b0;
                    float x1 = acc[mi][ni + 2][r] + b1;
                    C[(size_t)t * EMBED + col0] = (bf16)(x0 * c - x1 * s);
                    C[(size_t)t * EMBED + col1] = (bf16)(x1 * c + x0 * s);
                }
            }
        }
    } else {
        // V: bias + direct transposed store Vt[(h*64+d) * T + t] (8B per (mi,ni))
        const int hd0 = n0 + wn;                    // multiple of 64
        #pragma unroll
        for (int mi = 0; mi < 4; ++mi) {
            int trow = m0 + wm + mi * 16 + lq * 4;
            if (trow >= M) continue;
            #pragma unroll
            for (int ni = 0; ni < 4; ++ni) {
                int d = ni * 16 + ln;
                float bv = (float)vb[hd0 + d];
                bf16x4 o;
                #pragma unroll
                for (int r = 0; r < 4; ++r) o[r] = (bf16)(acc[mi][ni][r] + bv);
                *(bf16x4*)&Vt[(size_t)(hd0 + d) * T_TOTAL + trow] = o;
            }
        }
    }
}

// ---------------------------------------------------------------------------
// Out-proj GEMM: writes d_out directly (fp32 or bf16 per disc). Grid 77*8.
// ---------------------------------------------------------------------------
__global__ __launch_bounds__(256, 2)
void gemm_out(const bf16* __restrict__ A, const bf16* __restrict__ W,
              const bf16* __restrict__ bias, void* __restrict__ out, int M,
              const unsigned short* __restrict__ disc)
{
    __shared__ __align__(16) bf16 lds[4 * 8192];

    int x, yy;
    map_block(blockIdx.x, 8, x, yy);
    const int m0 = x * 128, n0 = yy * 128;

    f32x4 acc[4][4] = {};
    gemm_core128(A, W, M, m0, n0, acc, lds);

    const bool f32 = (disc[0] == 0);
    const int tid  = threadIdx.x;
    const int wave = tid >> 6, lane = tid & 63;
    const int ln   = lane & 15, lq = lane >> 4;
    const int wm = (wave & 1) * 64,  wn = (wave >> 1) * 64;

    #pragma unroll
    for (int mi = 0; mi < 4; ++mi) {
        int trow = m0 + wm + mi * 16 + lq * 4;
        if (trow >= M) continue;
        #pragma unroll
        for (int ni = 0; ni < 4; ++ni) {
            int col = n0 + wn + ni * 16 + ln;
            float bv = (float)bias[col];
            #pragma unroll
            for (int r = 0; r < 4; ++r) {
                float v = acc[mi][ni][r] + bv;
                size_t idx = (size_t)(trow + r) * EMBED + col;
                if (f32) ((float*)out)[idx] = v;
                else     ((bf16*)out)[idx]  = (bf16)v;
            }
        }
    }
}

// ---------------------------------------------------------------------------
// Flash attention, S^T formulation (unchanged — verified).
// ---------------------------------------------------------------------------
__global__ __launch_bounds__(256, 3)
void attn_kernel(const bf16* __restrict__ Q, const bf16* __restrict__ K,
                 const bf16* __restrict__ Vt, bf16* __restrict__ O)
{
    __shared__ __align__(16) bf16 sK[2][64 * 64];
    __shared__ __align__(16) bf16 sV[2][64 * 64];       // Vt tile: [dh][kv]
    __shared__ __align__(16) bf16 sQP[4 * 16 * 72];     // Q tile, later per-wave P

    const int tid  = threadIdx.x;
    const int wave = tid >> 6, lane = tid & 63;
    const int lrow = lane >> 3;
    const int gsw  = (lane & 7) ^ lrow;
    const int ln   = lane & 15, lq = lane >> 4;
    const int e7   = ln & 7;
    const int h = blockIdx.y;

    int b = 0;
    #pragma unroll
    for (int i = 1; i < 13; ++i) if ((int)blockIdx.x >= c_tiles_cum[i]) b = i;
    const int qt = blockIdx.x - c_tiles_cum[b];
    const int t0 = c_seq_start[b] + qt * 64;
    const int kvb0 = c_seq_start[b];

    for (int p = 0; p < 2; ++p) {
        int r = p * 32 + wave * 8;
        load_lds16(Q  + (size_t)(t0 + r + lrow) * EMBED + h * HDIM + gsw * 8, &sQP[r * 64]);
        load_lds16(K  + (size_t)(kvb0 + r + lrow) * EMBED + h * HDIM + gsw * 8, &sK[0][r * 64]);
        load_lds16(Vt + (size_t)(h * HDIM + r + lrow) * T_TOTAL + kvb0 + gsw * 8, &sV[0][r * 64]);
    }

    bf16x8 qf[2];
    f32x4 oacc[4] = {};
    float m_i = -1e30f, l_i = 0.0f;
    const float sc = 0.125f * 1.44269504088896f;
    const int q_loc = wave * 16 + ln;
    bf16* sP = &sQP[wave * 16 * 72];

    for (int j = 0; j <= qt; ++j) {
        __syncthreads();
        const int cur = j & 1;
        if (j == 0) {
            qf[0] = *(const bf16x8*)&sQP[q_loc * 64 + ((0 + lq) ^ e7) * 8];
            qf[1] = *(const bf16x8*)&sQP[q_loc * 64 + ((4 + lq) ^ e7) * 8];
            __syncthreads();
        }
        if (j < qt) {
            const int kvb = kvb0 + (j + 1) * 64;
            const int nxt = cur ^ 1;
            for (int p = 0; p < 2; ++p) {
                int r = p * 32 + wave * 8;
                load_lds16(K  + (size_t)(kvb + r + lrow) * EMBED + h * HDIM + gsw * 8, &sK[nxt][r * 64]);
                load_lds16(Vt + (size_t)(h * HDIM + r + lrow) * T_TOTAL + kvb + gsw * 8, &sV[nxt][r * 64]);
            }
        }

        f32x4 s[4] = {};
        #pragma unroll
        for (int kk = 0; kk < 2; ++kk)
            #pragma unroll
            for (int ni = 0; ni < 4; ++ni) {
                bf16x8 kf = *(const bf16x8*)&sK[cur][(ni * 16 + ln) * 64 + (((kk * 4 + lq) ^ e7) * 8)];
                s[ni] = mfma16(kf, qf[kk], s[ni]);      // S^T[kv][q]
            }

        float pb[4][4];
        if (j == qt) {
            #pragma unroll
            for (int ni = 0; ni < 4; ++ni)
                #pragma unroll
                for (int r = 0; r < 4; ++r) {
                    int kv = ni * 16 + lq * 4 + r;
                    pb[ni][r] = (kv <= q_loc) ? s[ni][r] * sc : -1e30f;
                }
        } else {
            #pragma unroll
            for (int ni = 0; ni < 4; ++ni)
                #pragma unroll
                for (int r = 0; r < 4; ++r)
                    pb[ni][r] = s[ni][r] * sc;
        }

        float mx = pb[0][0];
        #pragma unroll
        for (int ni = 0; ni < 4; ++ni)
            #pragma unroll
            for (int r = 0; r < 4; ++r) mx = fmaxf(mx, pb[ni][r]);
        mx = fmaxf(mx, __shfl_xor(mx, 16));
        mx = fmaxf(mx, __shfl_xor(mx, 32));
        float mnew  = fmaxf(m_i, mx);
        float alpha = exp2f(m_i - mnew);
        m_i = mnew;

        float rs = 0.0f;
        #pragma unroll
        for (int ni = 0; ni < 4; ++ni)
            #pragma unroll
            for (int r = 0; r < 4; ++r) {
                float pe = exp2f(pb[ni][r] - mnew);
                pb[ni][r] = pe;
                rs += pe;
            }
        rs += __shfl_xor(rs, 16);
        rs += __shfl_xor(rs, 32);
        l_i = l_i * alpha + rs;
        #pragma unroll
        for (int d = 0; d < 4; ++d)
            #pragma unroll
            for (int r = 0; r < 4; ++r) oacc[d][r] *= alpha;

        #pragma unroll
        for (int ni = 0; ni < 4; ++ni) {
            bf16x4 w4;
            #pragma unroll
            for (int r = 0; r < 4; ++r) w4[r] = (bf16)pb[ni][r];
            *(bf16x4*)&sP[ln * 72 + ni * 16 + lq * 4] = w4;
        }
        asm volatile("s_waitcnt lgkmcnt(0)" ::: "memory");

        #pragma unroll
        for (int kk = 0; kk < 2; ++kk) {
            bf16x8 pf = *(const bf16x8*)&sP[ln * 72 + kk * 32 + lq * 8];
            #pragma unroll
            for (int d = 0; d < 4; ++d) {
                bf16x8 vf = *(const bf16x8*)&sV[cur][(d * 16 + ln) * 64 + (((kk * 4 + lq) ^ e7) * 8)];
                oacc[d] = mfma16(vf, pf, oacc[d]);      // O^T[dh][q]
            }
        }
    }

    const float inv = 1.0f / l_i;
    const size_t row = (size_t)(t0 + q_loc) * EMBED + h * HDIM;
    #pragma unroll
    for (int d = 0; d < 4; ++d) {
        bf16x4 o4;
        #pragma unroll
        for (int r = 0; r < 4; ++r) o4[r] = (bf16)(oacc[d][r] * inv);
        *(bf16x4*)&O[row + d * 16 + lq * 4] = o4;
    }
}

// ---------------------------------------------------------------------------
extern "C" void kernel_launch(void* const* d_in, const int* in_sizes, int n_in,
                              void* d_out, int out_size, void* d_ws, size_t ws_size,
                              hipStream_t stream)
{
    const unsigned short* disc = (const unsigned short*)d_in[1];  // cos[0][0]

    const size_t SZ  = (size_t)T_TOTAL * EMBED;   // 10,027,008
    const size_t CS  = (size_t)T_TOTAL * HDIM;    // 626,688
    const size_t WSZ = (size_t)EMBED * EMBED;     // 1,048,576

    bf16* p = (bf16*)d_ws;
    bf16* ch   = p; p += SZ;
    bf16* ccos = p; p += CS;
    bf16* csin = p; p += CS;
    bf16* cqw  = p; p += WSZ;
    bf16* ckw  = p; p += WSZ;
    bf16* cvw  = p; p += WSZ;
    bf16* cow  = p; p += WSZ;
    bf16* cqb  = p; p += EMBED;
    bf16* cvb  = p; p += EMBED;
    bf16* cob  = p; p += EMBED;
    bf16* wq   = p; p += SZ;      // Q (post-RoPE), then attention output (in place)
    bf16* wk   = p; p += SZ;
    bf16* wvt  = p; p += SZ;      // V^T per head

    CvtArgs ca;
    const void* srcs[10] = {d_in[0], d_in[1], d_in[2], d_in[3], d_in[5],
                            d_in[6], d_in[8], d_in[4], d_in[7], d_in[9]};
    bf16* dsts[10] = {ch, ccos, csin, cqw, ckw, cvw, cow, cqb, cvb, cob};
    int   ns[10]   = {(int)SZ, (int)CS, (int)CS, (int)WSZ, (int)WSZ,
                      (int)WSZ, (int)WSZ, EMBED, EMBED, EMBED};
    int cum = 0;
    for (int i = 0; i < 10; ++i) {
        ca.src[i] = srcs[i]; ca.dst[i] = dsts[i]; ca.n[i] = ns[i];
        ca.cum[i] = cum;
        cum += (ns[i] + 2047) / 2048;
    }
    to_bf16_fused<<<cum, 256, 0, stream>>>(ca, disc);

    gemm_qkv<<<77 * 24, 256, 0, stream>>>(ch, cqw, ckw, cvw, cqb, cvb,
                                          ccos, csin, wq, wk, wvt, T_TOTAL);
    attn_kernel<<<dim3(153, 16), 256, 0, stream>>>(wq, wk, wvt, wq);
    gemm_out<<<77 * 8, 256, 0, stream>>>(wq, cow, cob, d_out, T_TOTAL, disc);
}

// Round 4
// 286.359 us; speedup vs baseline: 1.0814x; 1.0814x over previous
//
#include <hip/hip_runtime.h>

typedef __bf16 bf16;
typedef __bf16 bf16x8 __attribute__((ext_vector_type(8)));
typedef __bf16 bf16x4 __attribute__((ext_vector_type(4)));
typedef float  f32x4  __attribute__((ext_vector_type(4)));

#define T_TOTAL 9792
#define EMBED   1024
#define NHEAD   16
#define HDIM    64

// Fixed problem geometry (LENGTHS are compile-time constants of this problem).
__constant__ int c_seq_start[12] = {0,1024,1792,2688,3200,4224,4864,5888,6656,7168,8064,9088};
__constant__ int c_tiles_cum[13] = {0,16,28,42,50,66,76,92,104,112,126,142,153};

typedef __attribute__((address_space(1))) unsigned int gu32;
typedef __attribute__((address_space(3))) unsigned int lu32;

__device__ __forceinline__ void load_lds16(const void* g, void* l) {
    __builtin_amdgcn_global_load_lds((gu32*)g, (lu32*)l, 16, 0, 0);
}

__device__ __forceinline__ f32x4 mfma16(bf16x8 a, bf16x8 b, f32x4 c) {
    return __builtin_amdgcn_mfma_f32_16x16x32_bf16(a, b, c, 0, 0, 0);
}

// XCD-chunked remap (T1). MI355X: 8 XCDs, consecutive blockIdx round-robins
// XCDs; nwg%8==0 for all our grids -> bijective contiguous chunks per XCD.
__device__ __forceinline__ int xcd_chunk(int bid, int chunk) {
    return (bid & 7) * chunk + (bid >> 3);
}

// ---------------------------------------------------------------------------
// Fused dtype canonicalization: all 10 tensors in one dispatch.
// Discriminator: cos[0][0]==1.0 exactly -> fp32 first u16 is 0x0000.
// ---------------------------------------------------------------------------
struct CvtArgs {
    const void* src[10];
    bf16*       dst[10];
    int         n[10];
    int         cum[10];   // block offset of each segment
};

__global__ void to_bf16_fused(CvtArgs a, const unsigned short* __restrict__ disc)
{
    const bool f32 = (disc[0] == 0);
    const int blk = blockIdx.x;
    int seg = 0;
    #pragma unroll
    for (int i = 1; i < 10; ++i) if (blk >= a.cum[i]) seg = i;
    int i0 = (blk - a.cum[seg]) * 2048 + threadIdx.x * 8;
    if (i0 >= a.n[seg]) return;
    bf16x8 o;
    if (f32) {
        const float4* s = (const float4*)((const float*)a.src[seg] + i0);
        float4 x = s[0], y = s[1];
        o[0]=(bf16)x.x; o[1]=(bf16)x.y; o[2]=(bf16)x.z; o[3]=(bf16)x.w;
        o[4]=(bf16)y.x; o[5]=(bf16)y.y; o[6]=(bf16)y.z; o[7]=(bf16)y.w;
    } else {
        o = *(const bf16x8*)((const bf16*)a.src[seg] + i0);
    }
    *(bf16x8*)(a.dst[seg] + i0) = o;
}

// ---------------------------------------------------------------------------
// Shared GEMM core: acc = A[m0:+128] @ W[n0:+128]^T  (K=1024, BK=64).
// R0-verified structure (81 us, 0 bank conflicts): single 2x128x64 LDS,
// XOR-swizzled on the GLOBAL side of staging, 2 blocks/CU co-resident.
// ---------------------------------------------------------------------------
__device__ __forceinline__
void gemm_core(const bf16* __restrict__ A, const bf16* __restrict__ W,
               int M, int m0, int n0, f32x4 (&acc)[4][4],
               bf16* lA, bf16* lB)
{
    const int tid  = threadIdx.x;
    const int wave = tid >> 6, lane = tid & 63;
    const int lrow = lane >> 3;
    const int gsw  = (lane & 7) ^ lrow;
    const int ln   = lane & 15, lq = lane >> 4;
    const int e7   = ln & 7;
    const int wm = (wave & 1) * 64,  wn = (wave >> 1) * 64;

    for (int k0 = 0; k0 < 1024; k0 += 64) {
        __syncthreads();
        for (int j = 0; j < 4; ++j) {
            int r = j * 32 + wave * 8;
            int gr = m0 + r + lrow; if (gr > M - 1) gr = M - 1;
            load_lds16(A + (size_t)gr * EMBED + k0 + gsw * 8, &lA[r * 64]);
            load_lds16(W + (size_t)(n0 + r + lrow) * EMBED + k0 + gsw * 8, &lB[r * 64]);
        }
        __syncthreads();
        #pragma unroll
        for (int kb = 0; kb < 2; ++kb) {
            bf16x8 af[4], bfr[4];
            #pragma unroll
            for (int i = 0; i < 4; ++i)
                af[i]  = *(const bf16x8*)&lA[(wm + i * 16 + ln) * 64 + (((kb * 4 + lq) ^ e7) * 8)];
            #pragma unroll
            for (int i = 0; i < 4; ++i)
                bfr[i] = *(const bf16x8*)&lB[(wn + i * 16 + ln) * 64 + (((kb * 4 + lq) ^ e7) * 8)];
            #pragma unroll
            for (int mi = 0; mi < 4; ++mi)
                #pragma unroll
                for (int ni = 0; ni < 4; ++ni)
                    acc[mi][ni] = mfma16(af[mi], bfr[ni], acc[mi][ni]);
        }
    }
}

// Supertile block map: 8 x-tiles per super-column x all NY, L2/L3 locality.
__device__ __forceinline__ void map_block(int L, int NY, int& x, int& y)
{
    const int per = 8 * NY;
    const int full = 9 * per;          // 72 of 77 x-tiles in full supercols
    if (L < full) { int sc = L / per, rem = L % per; x = sc * 8 + (rem & 7); y = rem >> 3; }
    else          { int rem = L - full; x = 72 + rem % 5; y = rem / 5; }
}

// ---------------------------------------------------------------------------
// QKV fused GEMM. 1D grid 77*24 (=8*231, XCD-chunked). which = y>>3.
// Epilogue fuses: bias add, RoPE (Q,K; on fp32 acc), V transpose -> Vt.
// ---------------------------------------------------------------------------
__global__ __launch_bounds__(256, 2)
void gemm_qkv(const bf16* __restrict__ A,
              const bf16* __restrict__ Wq, const bf16* __restrict__ Wk,
              const bf16* __restrict__ Wv, const bf16* __restrict__ qb,
              const bf16* __restrict__ vb,
              const bf16* __restrict__ cosb, const bf16* __restrict__ sinb,
              bf16* __restrict__ Cq, bf16* __restrict__ Ck,
              bf16* __restrict__ Vt, int M)
{
    __shared__ __align__(16) bf16 lA[128 * 64];
    __shared__ __align__(16) bf16 lB[128 * 64];

    int x, yy;
    map_block(xcd_chunk(blockIdx.x, 231), 24, x, yy);
    const int which = yy >> 3;
    const int m0 = x * 128, n0 = (yy & 7) * 128;

    const bf16* W = (which == 0) ? Wq : (which == 1) ? Wk : Wv;
    f32x4 acc[4][4] = {};
    gemm_core(A, W, M, m0, n0, acc, lA, lB);

    const int tid  = threadIdx.x;
    const int wave = tid >> 6, lane = tid & 63;
    const int ln   = lane & 15, lq = lane >> 4;
    const int wm = (wave & 1) * 64,  wn = (wave >> 1) * 64;

    if (which < 2) {
        // Q or K: bias (Q only) + RoPE on fp32 acc. Pair (d, d+32) = (ni, ni+2).
        bf16* C = (which == 0) ? Cq : Ck;
        const bf16* bias = (which == 0) ? qb : nullptr;
        #pragma unroll
        for (int mi = 0; mi < 4; ++mi) {
            int trow = m0 + wm + mi * 16 + lq * 4;
            if (trow >= M) continue;
            #pragma unroll
            for (int ni = 0; ni < 2; ++ni) {
                int d    = ni * 16 + ln;           // in [0,32)
                int col0 = n0 + wn + d;
                int col1 = col0 + 32;
                float b0 = bias ? (float)bias[col0] : 0.0f;
                float b1 = bias ? (float)bias[col1] : 0.0f;
                #pragma unroll
                for (int r = 0; r < 4; ++r) {
                    int t = trow + r;
                    float c = (float)cosb[t * HDIM + d];
                    float s = (float)sinb[t * HDIM + d];
                    float x0 = acc[mi][ni][r] + b0;
                    float x1 = acc[mi][ni + 2][r] + b1;
                    C[(size_t)t * EMBED + col0] = (bf16)(x0 * c - x1 * s);
                    C[(size_t)t * EMBED + col1] = (bf16)(x1 * c + x0 * s);
                }
            }
        }
    } else {
        // V: bias + direct transposed store Vt[(h*64+d) * T + t] (8B per (mi,ni))
        const int hd0 = n0 + wn;                    // multiple of 64
        #pragma unroll
        for (int mi = 0; mi < 4; ++mi) {
            int trow = m0 + wm + mi * 16 + lq * 4;
            if (trow >= M) continue;
            #pragma unroll
            for (int ni = 0; ni < 4; ++ni) {
                int d = ni * 16 + ln;
                float bv = (float)vb[hd0 + d];
                bf16x4 o;
                #pragma unroll
                for (int r = 0; r < 4; ++r) o[r] = (bf16)(acc[mi][ni][r] + bv);
                *(bf16x4*)&Vt[(size_t)(hd0 + d) * T_TOTAL + trow] = o;
            }
        }
    }
}

// ---------------------------------------------------------------------------
// Out-proj GEMM: writes d_out directly (fp32 or bf16 per disc). Grid 77*8.
// ---------------------------------------------------------------------------
__global__ __launch_bounds__(256, 2)
void gemm_out(const bf16* __restrict__ A, const bf16* __restrict__ W,
              const bf16* __restrict__ bias, void* __restrict__ out, int M,
              const unsigned short* __restrict__ disc)
{
    __shared__ __align__(16) bf16 lA[128 * 64];
    __shared__ __align__(16) bf16 lB[128 * 64];

    int x, yy;
    map_block(xcd_chunk(blockIdx.x, 77), 8, x, yy);
    const int m0 = x * 128, n0 = yy * 128;

    f32x4 acc[4][4] = {};
    gemm_core(A, W, M, m0, n0, acc, lA, lB);

    const bool f32 = (disc[0] == 0);
    const int tid  = threadIdx.x;
    const int wave = tid >> 6, lane = tid & 63;
    const int ln   = lane & 15, lq = lane >> 4;
    const int wm = (wave & 1) * 64,  wn = (wave >> 1) * 64;

    #pragma unroll
    for (int mi = 0; mi < 4; ++mi) {
        int trow = m0 + wm + mi * 16 + lq * 4;
        if (trow >= M) continue;
        #pragma unroll
        for (int ni = 0; ni < 4; ++ni) {
            int col = n0 + wn + ni * 16 + ln;
            float bv = (float)bias[col];
            #pragma unroll
            for (int r = 0; r < 4; ++r) {
                float v = acc[mi][ni][r] + bv;
                size_t idx = (size_t)(trow + r) * EMBED + col;
                if (f32) ((float*)out)[idx] = v;
                else     ((bf16*)out)[idx]  = (bf16)v;
            }
        }
    }
}

// ---------------------------------------------------------------------------
// Flash attention, S^T formulation. 1D grid 2448 (=8*306, XCD-chunked:
// each XCD gets exactly 2 full heads -> balanced + per-XCD KV L2 reuse).
// New this round: T13 defer-max (skip O/l rescale when max grows <= 8 in
// log2 domain; P bounded by 256, f32 accum headroom fine; wave-uniform).
// ---------------------------------------------------------------------------
__global__ __launch_bounds__(256, 3)
void attn_kernel(const bf16* __restrict__ Q, const bf16* __restrict__ K,
                 const bf16* __restrict__ Vt, bf16* __restrict__ O)
{
    __shared__ __align__(16) bf16 sK[2][64 * 64];
    __shared__ __align__(16) bf16 sV[2][64 * 64];       // Vt tile: [dh][kv]
    __shared__ __align__(16) bf16 sQP[4 * 16 * 72];     // Q tile, later per-wave P

    const int tid  = threadIdx.x;
    const int wave = tid >> 6, lane = tid & 63;
    const int lrow = lane >> 3;
    const int gsw  = (lane & 7) ^ lrow;
    const int ln   = lane & 15, lq = lane >> 4;
    const int e7   = ln & 7;

    const int swz = xcd_chunk(blockIdx.x, 306);
    const int h  = swz / 153;
    const int qx = swz - h * 153;

    int b = 0;
    #pragma unroll
    for (int i = 1; i < 13; ++i) if (qx >= c_tiles_cum[i]) b = i;
    const int qt = qx - c_tiles_cum[b];
    const int t0 = c_seq_start[b] + qt * 64;
    const int kvb0 = c_seq_start[b];

    for (int p = 0; p < 2; ++p) {
        int r = p * 32 + wave * 8;
        load_lds16(Q  + (size_t)(t0 + r + lrow) * EMBED + h * HDIM + gsw * 8, &sQP[r * 64]);
        load_lds16(K  + (size_t)(kvb0 + r + lrow) * EMBED + h * HDIM + gsw * 8, &sK[0][r * 64]);
        load_lds16(Vt + (size_t)(h * HDIM + r + lrow) * T_TOTAL + kvb0 + gsw * 8, &sV[0][r * 64]);
    }

    bf16x8 qf[2];
    f32x4 oacc[4] = {};
    float m_i = -1e30f, l_i = 0.0f;
    const float sc = 0.125f * 1.44269504088896f;
    const int q_loc = wave * 16 + ln;
    bf16* sP = &sQP[wave * 16 * 72];

    for (int j = 0; j <= qt; ++j) {
        __syncthreads();
        const int cur = j & 1;
        if (j == 0) {
            qf[0] = *(const bf16x8*)&sQP[q_loc * 64 + ((0 + lq) ^ e7) * 8];
            qf[1] = *(const bf16x8*)&sQP[q_loc * 64 + ((4 + lq) ^ e7) * 8];
            __syncthreads();
        }
        if (j < qt) {
            const int kvb = kvb0 + (j + 1) * 64;
            const int nxt = cur ^ 1;
            for (int p = 0; p < 2; ++p) {
                int r = p * 32 + wave * 8;
                load_lds16(K  + (size_t)(kvb + r + lrow) * EMBED + h * HDIM + gsw * 8, &sK[nxt][r * 64]);
                load_lds16(Vt + (size_t)(h * HDIM + r + lrow) * T_TOTAL + kvb + gsw * 8, &sV[nxt][r * 64]);
            }
        }

        f32x4 s[4] = {};
        #pragma unroll
        for (int kk = 0; kk < 2; ++kk)
            #pragma unroll
            for (int ni = 0; ni < 4; ++ni) {
                bf16x8 kf = *(const bf16x8*)&sK[cur][(ni * 16 + ln) * 64 + (((kk * 4 + lq) ^ e7) * 8)];
                s[ni] = mfma16(kf, qf[kk], s[ni]);      // S^T[kv][q]
            }

        float pb[4][4];
        if (j == qt) {
            #pragma unroll
            for (int ni = 0; ni < 4; ++ni)
                #pragma unroll
                for (int r = 0; r < 4; ++r) {
                    int kv = ni * 16 + lq * 4 + r;
                    pb[ni][r] = (kv <= q_loc) ? s[ni][r] * sc : -1e30f;
                }
        } else {
            #pragma unroll
            for (int ni = 0; ni < 4; ++ni)
                #pragma unroll
                for (int r = 0; r < 4; ++r)
                    pb[ni][r] = s[ni][r] * sc;
        }

        float mx = pb[0][0];
        #pragma unroll
        for (int ni = 0; ni < 4; ++ni)
            #pragma unroll
            for (int r = 0; r < 4; ++r) mx = fmaxf(mx, pb[ni][r]);
        mx = fmaxf(mx, __shfl_xor(mx, 16));
        mx = fmaxf(mx, __shfl_xor(mx, 32));

        // T13 defer-max: only rescale when some row's max grew past m_i + 8.
        if (!__all(mx <= m_i + 8.0f)) {
            float mnew  = fmaxf(m_i, mx);
            float alpha = exp2f(m_i - mnew);
            l_i *= alpha;
            #pragma unroll
            for (int d = 0; d < 4; ++d)
                #pragma unroll
                for (int r = 0; r < 4; ++r) oacc[d][r] *= alpha;
            m_i = mnew;
        }

        float rs = 0.0f;
        #pragma unroll
        for (int ni = 0; ni < 4; ++ni)
            #pragma unroll
            for (int r = 0; r < 4; ++r) {
                float pe = exp2f(pb[ni][r] - m_i);
                pb[ni][r] = pe;
                rs += pe;
            }
        rs += __shfl_xor(rs, 16);
        rs += __shfl_xor(rs, 32);
        l_i += rs;

        #pragma unroll
        for (int ni = 0; ni < 4; ++ni) {
            bf16x4 w4;
            #pragma unroll
            for (int r = 0; r < 4; ++r) w4[r] = (bf16)pb[ni][r];
            *(bf16x4*)&sP[ln * 72 + ni * 16 + lq * 4] = w4;
        }
        asm volatile("s_waitcnt lgkmcnt(0)" ::: "memory");

        #pragma unroll
        for (int kk = 0; kk < 2; ++kk) {
            bf16x8 pf = *(const bf16x8*)&sP[ln * 72 + kk * 32 + lq * 8];
            #pragma unroll
            for (int d = 0; d < 4; ++d) {
                bf16x8 vf = *(const bf16x8*)&sV[cur][(d * 16 + ln) * 64 + (((kk * 4 + lq) ^ e7) * 8)];
                oacc[d] = mfma16(vf, pf, oacc[d]);      // O^T[dh][q]
            }
        }
    }

    const float inv = 1.0f / l_i;
    const size_t row = (size_t)(t0 + q_loc) * EMBED + h * HDIM;
    #pragma unroll
    for (int d = 0; d < 4; ++d) {
        bf16x4 o4;
        #pragma unroll
        for (int r = 0; r < 4; ++r) o4[r] = (bf16)(oacc[d][r] * inv);
        *(bf16x4*)&O[row + d * 16 + lq * 4] = o4;
    }
}

// ---------------------------------------------------------------------------
extern "C" void kernel_launch(void* const* d_in, const int* in_sizes, int n_in,
                              void* d_out, int out_size, void* d_ws, size_t ws_size,
                              hipStream_t stream)
{
    const unsigned short* disc = (const unsigned short*)d_in[1];  // cos[0][0]

    const size_t SZ  = (size_t)T_TOTAL * EMBED;   // 10,027,008
    const size_t CS  = (size_t)T_TOTAL * HDIM;    // 626,688
    const size_t WSZ = (size_t)EMBED * EMBED;     // 1,048,576

    bf16* p = (bf16*)d_ws;
    bf16* ch   = p; p += SZ;
    bf16* ccos = p; p += CS;
    bf16* csin = p; p += CS;
    bf16* cqw  = p; p += WSZ;
    bf16* ckw  = p; p += WSZ;
    bf16* cvw  = p; p += WSZ;
    bf16* cow  = p; p += WSZ;
    bf16* cqb  = p; p += EMBED;
    bf16* cvb  = p; p += EMBED;
    bf16* cob  = p; p += EMBED;
    bf16* wq   = p; p += SZ;      // Q (post-RoPE), then attention output (in place)
    bf16* wk   = p; p += SZ;
    bf16* wvt  = p; p += SZ;      // V^T per head

    CvtArgs ca;
    const void* srcs[10] = {d_in[0], d_in[1], d_in[2], d_in[3], d_in[5],
                            d_in[6], d_in[8], d_in[4], d_in[7], d_in[9]};
    bf16* dsts[10] = {ch, ccos, csin, cqw, ckw, cvw, cow, cqb, cvb, cob};
    int   ns[10]   = {(int)SZ, (int)CS, (int)CS, (int)WSZ, (int)WSZ,
                      (int)WSZ, (int)WSZ, EMBED, EMBED, EMBED};
    int cum = 0;
    for (int i = 0; i < 10; ++i) {
        ca.src[i] = srcs[i]; ca.dst[i] = dsts[i]; ca.n[i] = ns[i];
        ca.cum[i] = cum;
        cum += (ns[i] + 2047) / 2048;
    }
    to_bf16_fused<<<cum, 256, 0, stream>>>(ca, disc);

    gemm_qkv<<<77 * 24, 256, 0, stream>>>(ch, cqw, ckw, cvw, cqb, cvb,
                                          ccos, csin, wq, wk, wvt, T_TOTAL);
    attn_kernel<<<2448, 256, 0, stream>>>(wq, wk, wvt, wq);
    gemm_out<<<77 * 8, 256, 0, stream>>>(wq, cow, cob, d_out, T_TOTAL, disc);
}